// Round 5
// baseline (698.228 us; speedup 1.0000x reference)
//
#include <hip/hip_runtime.h>
#include <hip/hip_bf16.h>
#include <stdint.h>

// Problem constants (match reference)
#define B_SZ   16384
#define IN_DIM 1024
#define H1     2048
#define H2     2048
#define HID    1024
#define SPEC_H 2048
#define NE     8
#define MAX_TILES 136   // 8 XCDs x 17 tiles exactly

typedef __bf16 bf16x8 __attribute__((ext_vector_type(8)));
typedef float  f32x4  __attribute__((ext_vector_type(4)));

__device__ __forceinline__ ushort f2bf(float f) {
  uint32_t u = __float_as_uint(f);
  u += 0x7FFF + ((u >> 16) & 1);
  return (ushort)(u >> 16);
}

__device__ __forceinline__ void gl_lds16(const void* g, void* l) {
  __builtin_amdgcn_global_load_lds(
      (const __attribute__((address_space(1))) void*)g,
      (__attribute__((address_space(3))) void*)l, 16, 0, 0);
}

// ---------------- elementwise / transpose-cast ----------------

__global__ void cast_f32_bf16(const float* __restrict__ in,
                              ushort* __restrict__ out, int n) {
  int i = (blockIdx.x * 256 + threadIdx.x) * 4;
  if (i + 3 < n) {
    float4 v = *(const float4*)(in + i);
    ushort4 o;
    o.x = f2bf(v.x); o.y = f2bf(v.y); o.z = f2bf(v.z); o.w = f2bf(v.w);
    *(ushort4*)(out + i) = o;
  }
}

__global__ void transpose_cast(const float* __restrict__ in,
                               ushort* __restrict__ out, int K, int N) {
  __shared__ float tile[64][65];  // tile[n][k]
  int n0 = blockIdx.x * 64, k0 = blockIdx.y * 64;
  const float* src = in + (size_t)blockIdx.z * K * N;
  ushort* dst = out + (size_t)blockIdx.z * K * N;
  int t = threadIdx.x;
  int lk = t >> 4;
  int ln4 = (t & 15) * 4;
#pragma unroll
  for (int j = 0; j < 4; ++j) {
    int k = lk + j * 16;
    float4 v = *(const float4*)(src + (size_t)(k0 + k) * N + n0 + ln4);
    tile[ln4 + 0][k] = v.x;
    tile[ln4 + 1][k] = v.y;
    tile[ln4 + 2][k] = v.z;
    tile[ln4 + 3][k] = v.w;
  }
  __syncthreads();
  int kc = (t & 15) * 4;
  int nb = t >> 4;
#pragma unroll
  for (int j = 0; j < 4; ++j) {
    int nn = nb + j * 16;
    ushort4 o;
    o.x = f2bf(tile[nn][kc + 0]);
    o.y = f2bf(tile[nn][kc + 1]);
    o.z = f2bf(tile[nn][kc + 2]);
    o.w = f2bf(tile[nn][kc + 3]);
    *(ushort4*)(dst + (size_t)(n0 + nn) * K + k0 + kc) = o;
  }
}

// ---------------- routing (counting sort by expert) ----------------

__global__ void count_k(const int* __restrict__ d, int* __restrict__ counts) {
  int i = blockIdx.x * 256 + threadIdx.x;
  if (i < B_SZ) atomicAdd(&counts[d[i]], 1);
}

__global__ void build_k(const int* __restrict__ counts, int* __restrict__ catalog,
                        int* __restrict__ poff, int* __restrict__ cursors) {
  if (threadIdx.x == 0) {
    int off = 0;
    for (int e = 0; e < NE; ++e) {
      poff[e] = off * 128;
      int nt = (counts[e] + 127) >> 7;
      for (int i = 0; i < nt; ++i) catalog[off + i] = e;
      off += nt;
      cursors[e] = 0;
    }
    for (int i = off; i < MAX_TILES; ++i) catalog[i] = -1;
  }
}

__global__ void scatter_k(const int* __restrict__ d, const int* __restrict__ poff,
                          int* __restrict__ cursors, int* __restrict__ perm) {
  int i = blockIdx.x * 256 + threadIdx.x;
  if (i < B_SZ) {
    int e = d[i];
    int p = atomicAdd(&cursors[e], 1);
    perm[poff[e] + p] = i;
  }
}

__global__ void init_out_k(const int* __restrict__ d, const float* __restrict__ b2,
                           float* __restrict__ out) {
  int i = blockIdx.x * 256 + threadIdx.x;
  if (i < B_SZ) out[i] = b2[d[i]];
}

// ---------------- 128x128 bf16 GEMM (proven; G1/G3) ----------------

template <int RELU>
__global__ __launch_bounds__(256, 2) void gemm_bias(
    const ushort* __restrict__ A, const ushort* __restrict__ Bt,
    const float* __restrict__ bias, ushort* __restrict__ C,
    int M, int N, int K, int lognx) {
  __shared__ __align__(16) ushort lA[128 * 64];
  __shared__ __align__(16) ushort lB[128 * 64];
  const int t = threadIdx.x;
  const int h = blockIdx.x;
  const int g = h >> 3;
  const int nx = 1 << lognx;
  const int by = (h & 7) + ((g >> lognx) << 3);
  const int bx = g & (nx - 1);
  const int m0 = by * 128, n0 = bx * 128;
  const int w = t >> 6, lane = t & 63;
  const int wm = (w >> 1) * 64, wn = (w & 1) * 64;
  const int q = lane >> 4, rl = lane & 15;

  f32x4 acc[4][4];
#pragma unroll
  for (int mi = 0; mi < 4; ++mi)
#pragma unroll
    for (int ni = 0; ni < 4; ++ni) acc[mi][ni] = 0.0f;

  const int row_s = t >> 3;
  const int pch_s = t & 7;

  for (int k0 = 0; k0 < K; k0 += 64) {
    __syncthreads();
#pragma unroll
    for (int j = 0; j < 4; ++j) {
      int row = j * 32 + row_s;
      int gch = pch_s ^ (row & 7);
      gl_lds16(A + (size_t)(m0 + row) * K + k0 + gch * 8, lA + j * 2048 + w * 512);
      gl_lds16(Bt + (size_t)(n0 + row) * K + k0 + gch * 8, lB + j * 2048 + w * 512);
    }
    __syncthreads();
#pragma unroll
    for (int kk = 0; kk < 2; ++kk) {
      bf16x8 af[4], bfr[4];
#pragma unroll
      for (int i = 0; i < 4; ++i) {
        int pc = (kk * 4 + q) ^ (rl & 7);
        af[i]  = __builtin_bit_cast(bf16x8, *(const int4*)(lA + (wm + i * 16 + rl) * 64 + pc * 8));
        bfr[i] = __builtin_bit_cast(bf16x8, *(const int4*)(lB + (wn + i * 16 + rl) * 64 + pc * 8));
      }
#pragma unroll
      for (int mi = 0; mi < 4; ++mi)
#pragma unroll
        for (int ni = 0; ni < 4; ++ni)
          acc[mi][ni] = __builtin_amdgcn_mfma_f32_16x16x32_bf16(af[mi], bfr[ni], acc[mi][ni], 0, 0, 0);
    }
  }

  float bv[4];
#pragma unroll
  for (int ni = 0; ni < 4; ++ni) bv[ni] = bias[n0 + wn + ni * 16 + rl];
#pragma unroll
  for (int mi = 0; mi < 4; ++mi) {
    int rg = m0 + wm + mi * 16 + q * 4;
#pragma unroll
    for (int r = 0; r < 4; ++r) {
#pragma unroll
      for (int ni = 0; ni < 4; ++ni) {
        float v = acc[mi][ni][r] + bv[ni];
        if (RELU) v = fmaxf(v, 0.0f);
        C[(size_t)(rg + r) * N + n0 + wn + ni * 16 + rl] = f2bf(v);
      }
    }
  }
}

// ---------------- 256x128 bf16 GEMM (higher LDS efficiency; G2) ----------------
// Wave-tile 128x64 (acc 8x4). LDS traffic/FLOP 0.75x of 128^2 kernel.
// Requires M%256==0, (M/256)%8==0, N/128 = 2^lognx.

template <int RELU>
__global__ __launch_bounds__(256, 2) void gemm_bias_256(
    const ushort* __restrict__ A, const ushort* __restrict__ Bt,
    const float* __restrict__ bias, ushort* __restrict__ C,
    int M, int N, int K, int lognx) {
  __shared__ __align__(16) ushort lA[256 * 64];
  __shared__ __align__(16) ushort lB[128 * 64];
  const int t = threadIdx.x;
  const int h = blockIdx.x;
  const int g = h >> 3;
  const int nx = 1 << lognx;
  const int by = (h & 7) + ((g >> lognx) << 3);
  const int bx = g & (nx - 1);
  const int m0 = by * 256, n0 = bx * 128;
  const int w = t >> 6, lane = t & 63;
  const int wm = (w >> 1) * 128, wn = (w & 1) * 64;
  const int q = lane >> 4, rl = lane & 15;

  f32x4 acc[8][4];
#pragma unroll
  for (int mi = 0; mi < 8; ++mi)
#pragma unroll
    for (int ni = 0; ni < 4; ++ni) acc[mi][ni] = 0.0f;

  const int row_s = t >> 3;
  const int pch_s = t & 7;

  for (int k0 = 0; k0 < K; k0 += 64) {
    __syncthreads();
#pragma unroll
    for (int j = 0; j < 8; ++j) {
      int row = j * 32 + row_s;
      int gch = pch_s ^ (row & 7);
      gl_lds16(A + (size_t)(m0 + row) * K + k0 + gch * 8, lA + j * 2048 + w * 512);
    }
#pragma unroll
    for (int j = 0; j < 4; ++j) {
      int row = j * 32 + row_s;
      int gch = pch_s ^ (row & 7);
      gl_lds16(Bt + (size_t)(n0 + row) * K + k0 + gch * 8, lB + j * 2048 + w * 512);
    }
    __syncthreads();
#pragma unroll
    for (int kk = 0; kk < 2; ++kk) {
      bf16x8 bfr[4];
#pragma unroll
      for (int i = 0; i < 4; ++i) {
        int pc = (kk * 4 + q) ^ (rl & 15 & 7);
        bfr[i] = __builtin_bit_cast(bf16x8, *(const int4*)(lB + (wn + i * 16 + rl) * 64 + pc * 8));
      }
#pragma unroll
      for (int mi = 0; mi < 8; ++mi) {
        int pc = (kk * 4 + q) ^ (rl & 7);
        bf16x8 af = __builtin_bit_cast(bf16x8, *(const int4*)(lA + (wm + mi * 16 + rl) * 64 + pc * 8));
#pragma unroll
        for (int ni = 0; ni < 4; ++ni)
          acc[mi][ni] = __builtin_amdgcn_mfma_f32_16x16x32_bf16(af, bfr[ni], acc[mi][ni], 0, 0, 0);
      }
    }
  }

  float bv[4];
#pragma unroll
  for (int ni = 0; ni < 4; ++ni) bv[ni] = bias[n0 + wn + ni * 16 + rl];
#pragma unroll
  for (int mi = 0; mi < 8; ++mi) {
    int rg = m0 + wm + mi * 16 + q * 4;
#pragma unroll
    for (int r = 0; r < 4; ++r) {
#pragma unroll
      for (int ni = 0; ni < 4; ++ni) {
        float v = acc[mi][ni][r] + bv[ni];
        if (RELU) v = fmaxf(v, 0.0f);
        C[(size_t)(rg + r) * N + n0 + wn + ni * 16 + rl] = f2bf(v);
      }
    }
  }
}

// ---------------- fused expert stage ----------------
// 1-D grid, XCD-partitioned: XCD k (id%8) gets tiles [17k,17k+17) x 16 ycols.
// Tiles are expert-sorted -> each XCD touches <=2 experts' W1 -> minimal L2 dup.
__global__ __launch_bounds__(256, 2) void expert_fused(
    const ushort* __restrict__ Z, const ushort* __restrict__ W1t,
    const float* __restrict__ b1, const float* __restrict__ w2,
    const int* __restrict__ perm, const int* __restrict__ catalog,
    float* __restrict__ out) {
  const int id = blockIdx.x;
  const int tile = (id & 7) * 17 + ((id >> 3) >> 4);
  const int ycol = (id >> 3) & 15;
  int e = catalog[tile];
  if (e < 0) return;
  __shared__ __align__(16) ushort lA[128 * 64];
  __shared__ __align__(16) ushort lB[128 * 64];
  __shared__ int perml[128];
  __shared__ float ysum[128];
  const int t = threadIdx.x;
  if (t < 128) {
    perml[t] = perm[tile * 128 + t];
    ysum[t] = 0.0f;
  }
  __syncthreads();

  const int n0 = ycol * 128;
  const ushort* Bt = W1t + (size_t)e * SPEC_H * HID;
  const float* b1e = b1 + (size_t)e * SPEC_H;
  const float* w2e = w2 + (size_t)e * SPEC_H;
  const int w = t >> 6, lane = t & 63;
  const int wm = (w >> 1) * 64, wn = (w & 1) * 64;
  const int q = lane >> 4, rl = lane & 15;

  f32x4 acc[4][4];
#pragma unroll
  for (int mi = 0; mi < 4; ++mi)
#pragma unroll
    for (int ni = 0; ni < 4; ++ni) acc[mi][ni] = 0.0f;

  const int row_s = t >> 3;
  const int pch_s = t & 7;

  for (int k0 = 0; k0 < HID; k0 += 64) {
    __syncthreads();
#pragma unroll
    for (int j = 0; j < 4; ++j) {
      int row = j * 32 + row_s;
      int gch = pch_s ^ (row & 7);
      int zr = perml[row];
      zr = zr < 0 ? 0 : zr;
      gl_lds16(Z + (size_t)zr * HID + k0 + gch * 8, lA + j * 2048 + w * 512);
      gl_lds16(Bt + (size_t)(n0 + row) * HID + k0 + gch * 8, lB + j * 2048 + w * 512);
    }
    __syncthreads();
#pragma unroll
    for (int kk = 0; kk < 2; ++kk) {
      bf16x8 af[4], bfr[4];
#pragma unroll
      for (int i = 0; i < 4; ++i) {
        int pc = (kk * 4 + q) ^ (rl & 7);
        af[i]  = __builtin_bit_cast(bf16x8, *(const int4*)(lA + (wm + i * 16 + rl) * 64 + pc * 8));
        bfr[i] = __builtin_bit_cast(bf16x8, *(const int4*)(lB + (wn + i * 16 + rl) * 64 + pc * 8));
      }
#pragma unroll
      for (int mi = 0; mi < 4; ++mi)
#pragma unroll
        for (int ni = 0; ni < 4; ++ni)
          acc[mi][ni] = __builtin_amdgcn_mfma_f32_16x16x32_bf16(af[mi], bfr[ni], acc[mi][ni], 0, 0, 0);
    }
  }

  float w2v[4], b1v[4];
#pragma unroll
  for (int ni = 0; ni < 4; ++ni) {
    int n = n0 + wn + ni * 16 + rl;
    w2v[ni] = w2e[n];
    b1v[ni] = b1e[n];
  }
#pragma unroll
  for (int mi = 0; mi < 4; ++mi) {
#pragma unroll
    for (int r = 0; r < 4; ++r) {
      float p = 0.0f;
#pragma unroll
      for (int ni = 0; ni < 4; ++ni) {
        float h = acc[mi][ni][r] + b1v[ni];
        h = fmaxf(h, 0.0f);
        p += h * w2v[ni];
      }
      p += __shfl_xor(p, 1);
      p += __shfl_xor(p, 2);
      p += __shfl_xor(p, 4);
      p += __shfl_xor(p, 8);
      if (rl == 0) atomicAdd(&ysum[wm + mi * 16 + q * 4 + r], p);
    }
  }
  __syncthreads();
  if (t < 128) {
    int orow = perml[t];
    if (orow >= 0) atomicAdd(&out[orow], ysum[t]);
  }
}

// ---------------- host ----------------

extern "C" void kernel_launch(void* const* d_in, const int* in_sizes, int n_in,
                              void* d_out, int out_size, void* d_ws, size_t ws_size,
                              hipStream_t stream) {
  const float* x   = (const float*)d_in[0];
  const int*   d   = (const int*)d_in[1];
  const float* eW0 = (const float*)d_in[2];
  const float* eb0 = (const float*)d_in[3];
  const float* eW1 = (const float*)d_in[4];
  const float* eb1 = (const float*)d_in[5];
  const float* eW2 = (const float*)d_in[6];
  const float* eb2 = (const float*)d_in[7];
  const float* sW1 = (const float*)d_in[8];
  const float* sb1 = (const float*)d_in[9];
  const float* sW2 = (const float*)d_in[10];
  const float* sb2 = (const float*)d_in[11];
  float* out = (float*)d_out;

  const size_t fixed = ((size_t)(4 + 8 + 4 + 32 + 32) << 20) + (1 << 20);
  int CH = 4096;
  if (ws_size >= fixed + (size_t)16384 * 10240) CH = 16384;
  else if (ws_size >= fixed + (size_t)8192 * 10240) CH = 8192;

  char* p = (char*)d_ws;
  ushort* W0t  = (ushort*)p; p += (size_t)IN_DIM * H1 * 2;
  ushort* W1t  = (ushort*)p; p += (size_t)H1 * H2 * 2;
  ushort* W2t  = (ushort*)p; p += (size_t)H2 * HID * 2;
  ushort* sW1t = (ushort*)p; p += (size_t)NE * HID * SPEC_H * 2;
  ushort* Zb   = (ushort*)p; p += (size_t)B_SZ * HID * 2;
  int* counts  = (int*)p; p += 64;
  int* cursors = (int*)p; p += 64;
  int* poff    = (int*)p; p += 64;
  int* catalog = (int*)p; p += 1024;
  int* perm    = (int*)p; p += (size_t)MAX_TILES * 128 * 4;
  p = (char*)(((uintptr_t)p + 255) & ~(uintptr_t)255);
  ushort* xb_c = (ushort*)p; p += (size_t)CH * IN_DIM * 2;
  ushort* z1_c = (ushort*)p; p += (size_t)CH * H1 * 2;
  ushort* z2_c = (ushort*)p; p += (size_t)CH * H2 * 2;

  hipMemsetAsync(counts, 0, 64, stream);
  hipMemsetAsync(perm, 0xFF, (size_t)MAX_TILES * 128 * 4, stream);

  count_k<<<B_SZ / 256, 256, 0, stream>>>(d, counts);
  build_k<<<1, 64, 0, stream>>>(counts, catalog, poff, cursors);
  scatter_k<<<B_SZ / 256, 256, 0, stream>>>(d, poff, cursors, perm);
  init_out_k<<<B_SZ / 256, 256, 0, stream>>>(d, sb2, out);

  transpose_cast<<<dim3(H1 / 64, IN_DIM / 64, 1), 256, 0, stream>>>(eW0, W0t, IN_DIM, H1);
  transpose_cast<<<dim3(H2 / 64, H1 / 64, 1), 256, 0, stream>>>(eW1, W1t, H1, H2);
  transpose_cast<<<dim3(HID / 64, H2 / 64, 1), 256, 0, stream>>>(eW2, W2t, H2, HID);
  transpose_cast<<<dim3(SPEC_H / 64, HID / 64, NE), 256, 0, stream>>>(sW1, sW1t, HID, SPEC_H);

  for (int c = 0; c < B_SZ; c += CH) {
    cast_f32_bf16<<<(CH * IN_DIM) / 1024, 256, 0, stream>>>(
        x + (size_t)c * IN_DIM, xb_c, CH * IN_DIM);
    gemm_bias<1><<<(CH / 128) * (H1 / 128), 256, 0, stream>>>(
        xb_c, W0t, eb0, z1_c, CH, H1, IN_DIM, 4);
    gemm_bias_256<1><<<(CH / 256) * (H2 / 128), 256, 0, stream>>>(
        z1_c, W1t, eb1, z2_c, CH, H2, H1, 4);
    gemm_bias<0><<<(CH / 128) * (HID / 128), 256, 0, stream>>>(
        z2_c, W2t, eb2, Zb + (size_t)c * HID, CH, HID, H2, 3);
  }

  expert_fused<<<MAX_TILES * 16, 256, 0, stream>>>(
      Zb, sW1t, sb1, sW2, perm, catalog, out);
}